// Round 3
// baseline (361.041 us; speedup 1.0000x reference)
//
#include <hip/hip_runtime.h>

// QuantumLayer: h = x @ W + b  (B x 1024 @ 1024 x 2), row-normalize h,
// then a fixed 2-qubit circuit -> [B,2] <Z> values.
// HBM-bound on reading x (268 MB).
// R3: half-wave-per-row pairing — lanes 0..31 own even row, 32..63 odd row.
// Butterfly needs only 5 levels (xor<32 stays in half); each lane runs the
// circuit for its own row only. Tail work per row: 5 shuffles + 0.5 circuits
// (vs 12 shuffles + 1 redundant circuit before). 16 rows/wave, unrolled.

#define WAVES_PER_BLOCK 4
#define ROWS_PER_WAVE   16
#define ROWS_PER_BLOCK  (WAVES_PER_BLOCK * ROWS_PER_WAVE)  // 64

__device__ __forceinline__ float2 run_circuit(
    float h0, float h1,
    float c00, float s00, float c01, float s01,   // layer 0: wire0, wire1
    float c10, float s10, float c11, float s11)   // layer 1: wire0, wire1
{
    float inv = rsqrtf(fmaxf(h0 * h0 + h1 * h1, 1e-12f));
    float t0 = 0.5f * h0 * inv;
    float t1 = 0.5f * h1 * inv;
    float s0 = __sinf(t0), c0 = __cosf(t0);
    float s1 = __sinf(t1), c1 = __cosf(t1);

    // state after RX(h0) wire0, RX(h1) wire1 on |00>:
    float r00 = c0 * c1,   i00 = 0.0f;
    float r01 = 0.0f,      i01 = -c0 * s1;
    float r10 = 0.0f,      i10 = -s0 * c1;
    float r11 = -s0 * s1,  i11 = 0.0f;

    float ar, ai, br, bi, tr, ti;

#define RX_W0(c, s)                                                  \
    ar = r00; ai = i00; br = r10; bi = i10;                          \
    r00 = c * ar + s * bi; i00 = c * ai - s * br;                    \
    r10 = s * ai + c * br; i10 = c * bi - s * ar;                    \
    ar = r01; ai = i01; br = r11; bi = i11;                          \
    r01 = c * ar + s * bi; i01 = c * ai - s * br;                    \
    r11 = s * ai + c * br; i11 = c * bi - s * ar;

#define RX_W1(c, s)                                                  \
    ar = r00; ai = i00; br = r01; bi = i01;                          \
    r00 = c * ar + s * bi; i00 = c * ai - s * br;                    \
    r01 = s * ai + c * br; i01 = c * bi - s * ar;                    \
    ar = r10; ai = i10; br = r11; bi = i11;                          \
    r10 = c * ar + s * bi; i10 = c * ai - s * br;                    \
    r11 = s * ai + c * br; i11 = c * bi - s * ar;

#define CNOT01()                                                     \
    tr = r10; ti = i10; r10 = r11; i10 = i11; r11 = tr; i11 = ti;

    RX_W0(c00, s00)
    RX_W1(c01, s01)
    CNOT01()
    RX_W0(c10, s10)
    RX_W1(c11, s11)
    CNOT01()

#undef RX_W0
#undef RX_W1
#undef CNOT01

    float p00 = r00 * r00 + i00 * i00;
    float p01 = r01 * r01 + i01 * i01;
    float p10 = r10 * r10 + i10 * i10;
    float p11 = r11 * r11 + i11 * i11;

    float2 z;
    z.x = (p00 + p01) - (p10 + p11);
    z.y = (p00 + p10) - (p01 + p11);
    return z;
}

__global__ __launch_bounds__(256) void qlayer_kernel(
    const float* __restrict__ x,    // [B,1024]
    const float* __restrict__ w,    // [1024,2] row-major: w[d*2+q]
    const float* __restrict__ bias, // [2]
    const float* __restrict__ wq,   // [2,2]
    float* __restrict__ out,        // [B,2]
    int B)
{
    const int lane = threadIdx.x & 63;
    const int li   = lane & 31;   // index within half-wave
    const int half = lane >> 5;   // 0 -> even row of pair, 1 -> odd row
    const int wave = threadIdx.x >> 6;
    const int rowBase = (blockIdx.x * WAVES_PER_BLOCK + wave) * ROWS_PER_WAVE;
    if (rowBase >= B) return;

    // Lane handles float4-indices f = li + 32*j (j=0..7) of its row
    // (256 float4 per row over 32 lanes). Weight fragment for d=4f is the
    // two float4 at w4[2f], w4[2f+1]. Same for both halves (same li).
    const float4* __restrict__ w4 = (const float4*)w;
    float4 wA[8], wB[8];
#pragma unroll
    for (int j = 0; j < 8; ++j) {
        const int f = li + 32 * j;
        wA[j] = w4[2 * f];
        wB[j] = w4[2 * f + 1];
    }

    const float b0 = bias[0], b1 = bias[1];

    const float c00 = __cosf(0.5f * wq[0]), s00 = __sinf(0.5f * wq[0]);
    const float c01 = __cosf(0.5f * wq[1]), s01 = __sinf(0.5f * wq[1]);
    const float c10 = __cosf(0.5f * wq[2]), s10 = __sinf(0.5f * wq[2]);
    const float c11 = __cosf(0.5f * wq[3]), s11 = __sinf(0.5f * wq[3]);

    float2* __restrict__ out2 = (float2*)out;

#pragma unroll
    for (int p = 0; p < ROWS_PER_WAVE / 4; ++p) {
        const int r0 = rowBase + 4 * p;     // this pass: rows r0 .. r0+3
        if (r0 + 3 >= B + 0 && r0 >= B) break;  // (B % 64 == 0 in practice)

        // pair0 = rows (r0, r0+1); pair1 = rows (r0+2, r0+3).
        // This lane reads row r0 + half (pair0) and r0 + 2 + half (pair1).
        const float4* __restrict__ x0 = (const float4*)x + (size_t)(r0 + half) * 256;
        const float4* __restrict__ x1 = (const float4*)x + (size_t)(r0 + 2 + half) * 256;

        // Issue all 16 loads up front.
        float4 v0[8], v1[8];
#pragma unroll
        for (int j = 0; j < 8; ++j) v0[j] = x0[li + 32 * j];
#pragma unroll
        for (int j = 0; j < 8; ++j) v1[j] = x1[li + 32 * j];

        float a0 = 0.f, a1 = 0.f, e0 = 0.f, e1 = 0.f;
#pragma unroll
        for (int j = 0; j < 8; ++j) {
            a0 = fmaf(v0[j].x, wA[j].x, a0); a1 = fmaf(v0[j].x, wA[j].y, a1);
            a0 = fmaf(v0[j].y, wA[j].z, a0); a1 = fmaf(v0[j].y, wA[j].w, a1);
            a0 = fmaf(v0[j].z, wB[j].x, a0); a1 = fmaf(v0[j].z, wB[j].y, a1);
            a0 = fmaf(v0[j].w, wB[j].z, a0); a1 = fmaf(v0[j].w, wB[j].w, a1);
            e0 = fmaf(v1[j].x, wA[j].x, e0); e1 = fmaf(v1[j].x, wA[j].y, e1);
            e0 = fmaf(v1[j].y, wA[j].z, e0); e1 = fmaf(v1[j].y, wA[j].w, e1);
            e0 = fmaf(v1[j].z, wB[j].x, e0); e1 = fmaf(v1[j].z, wB[j].y, e1);
            e0 = fmaf(v1[j].w, wB[j].z, e0); e1 = fmaf(v1[j].w, wB[j].w, e1);
        }

        // Butterfly within each 32-lane half (xor offsets < 32 stay inside).
#pragma unroll
        for (int off = 16; off >= 1; off >>= 1) {
            a0 += __shfl_xor(a0, off, 64);
            a1 += __shfl_xor(a1, off, 64);
            e0 += __shfl_xor(e0, off, 64);
            e1 += __shfl_xor(e1, off, 64);
        }

        // Each lane's half owns one row per pair; li==0 lanes (0 and 32) store.
        float2 z0 = run_circuit(a0 + b0, a1 + b1, c00, s00, c01, s01, c10, s10, c11, s11);
        float2 z1 = run_circuit(e0 + b0, e1 + b1, c00, s00, c01, s01, c10, s10, c11, s11);

        if (li == 0) {
            out2[r0 + half]     = z0;
            out2[r0 + 2 + half] = z1;
        }
    }
}

extern "C" void kernel_launch(void* const* d_in, const int* in_sizes, int n_in,
                              void* d_out, int out_size, void* d_ws, size_t ws_size,
                              hipStream_t stream) {
    const float* x    = (const float*)d_in[0];
    const float* w    = (const float*)d_in[1];
    const float* bias = (const float*)d_in[2];
    const float* wq   = (const float*)d_in[3];
    float* out = (float*)d_out;

    const int B = in_sizes[0] / 1024;
    const int grid = (B + ROWS_PER_BLOCK - 1) / ROWS_PER_BLOCK;
    qlayer_kernel<<<grid, 256, 0, stream>>>(x, w, bias, wq, out, B);
}